// Round 3
// baseline (1072.251 us; speedup 1.0000x reference)
//
#include <hip/hip_runtime.h>

#define BB   16
#define CCH  256
#define HH   96
#define WW   96
#define HW   (HH * WW)          // 9216
#define PHD  9
#define PWD  9
#define RAD  4
#define TH   16                 // tile h
#define TW   32                 // tile w
#define WL   8                  // w per lane
#define CC   8                  // channels per LDS chunk
#define NCHUNK (CCH / CC)       // 32
#define DPG  3                  // dh per group (one per wave)
#define NTHREADS 192            // 3 waves
#define S2ROWS (TH + DPG - 1)   // 18
#define S2W    44               // padded row (40 used) -> conflict-free b128 phases
#define S2CH   (S2ROWS * S2W)   // 792 floats per channel
#define S2ELEMS (CC * S2CH)     // 6336 floats = 25,344 B
#define NSLOT  (CC * S2ROWS * 10)  // 1440 float4 staging slots

__global__ __launch_bounds__(NTHREADS, 3)
void corr_kernel(const float* __restrict__ in1,
                 const float* __restrict__ in2,
                 float* __restrict__ out) {
    __shared__ float s2[S2ELEMS];

    const int tid = threadIdx.x;
    const int dhg = blockIdx.x % 3;       // dh group, fastest-varying
    const int wt  = blockIdx.x / 3;       // 0..2
    const int h0  = blockIdx.y * TH;
    const int b   = blockIdx.z;
    const int w0  = wt * TW;

    const float* p1 = in1 + (size_t)b * CCH * HW;
    const float* p2 = in2 + (size_t)b * CCH * HW;

    // ---- staging descriptors for s2 (8 float4 slots / thread, reused every chunk)
    // slot -> (ch, row, c4); global float4 fully-in or fully-out (halo 4 = f4 width)
    int gofs[8];
    int lofs[8];
    const int rowbase = h0 + dhg * DPG - RAD;   // global row of s2 row 0
    #pragma unroll
    for (int k = 0; k < 8; ++k) {
        int slot = tid + k * NTHREADS;
        if (slot < NSLOT) {
            int ch  = slot / (S2ROWS * 10);
            int rem = slot - ch * (S2ROWS * 10);
            int row = rem / 10;
            int c4  = rem - row * 10;
            int grow = rowbase + row;
            int gcb  = w0 - RAD + c4 * 4;
            bool valid = ((unsigned)grow < HH) && ((unsigned)gcb < WW);
            gofs[k] = valid ? (ch * HW + grow * WW + gcb) : -1;
            lofs[k] = ch * S2CH + row * S2W + c4 * 4;
        } else { gofs[k] = -1; lofs[k] = 0; }
    }
    const bool wr[8] = { tid + 0*NTHREADS < NSLOT, tid + 1*NTHREADS < NSLOT,
                         tid + 2*NTHREADS < NSLOT, tid + 3*NTHREADS < NSLOT,
                         tid + 4*NTHREADS < NSLOT, tid + 5*NTHREADS < NSLOT,
                         tid + 6*NTHREADS < NSLOT, tid + 7*NTHREADS < NSLOT };

    const float4 z4 = make_float4(0.f, 0.f, 0.f, 0.f);

    // ---- prefetch chunk 0
    float4 r2[8];
    #pragma unroll
    for (int k = 0; k < 8; ++k)
        r2[k] = (gofs[k] >= 0) ? *(const float4*)(p2 + gofs[k]) : z4;

    // ---- lane decode
    const int lane = tid & 63;
    const int wv   = tid >> 6;        // 0..2 ; ph = dhg*3 + wv
    const int ly   = lane >> 2;       // 0..15 (tile row)
    const int lx   = lane & 3;        // 0..3  (8-float col group)

    const int a_ofs = (h0 + ly) * WW + w0 + lx * WL;       // in1 float offset (per channel)
    const int s2_ro = (ly + wv) * S2W + lx * WL;           // in-channel LDS float offset

    float acc[PWD][WL];
    #pragma unroll
    for (int pw = 0; pw < PWD; ++pw)
        #pragma unroll
        for (int r = 0; r < WL; ++r) acc[pw][r] = 0.f;

    for (int t = 0; t < NCHUNK; ++t) {
        __syncthreads();   // previous chunk's reads done
        #pragma unroll
        for (int k = 0; k < 8; ++k)
            if (wr[k]) *(float4*)(s2 + lofs[k]) = r2[k];
        __syncthreads();   // s2 ready

        // prefetch next chunk's in2 (latency hides under compute)
        if (t + 1 < NCHUNK) {
            const float* q2 = p2 + (size_t)(t + 1) * CC * HW;
            #pragma unroll
            for (int k = 0; k < 8; ++k)
                r2[k] = (gofs[k] >= 0) ? *(const float4*)(q2 + gofs[k]) : z4;
        }

        // compute: 8 channels x (2 global a-loads + 4 ds_read_b128 + 72 FMA)
        const float* pc = p1 + (size_t)t * CC * HW + a_ofs;
        #pragma unroll
        for (int c = 0; c < CC; ++c) {
            float4 a0 = *(const float4*)(pc + c * HW);
            float4 a1 = *(const float4*)(pc + c * HW + 4);
            const float* brow = s2 + c * S2CH + s2_ro;
            float4 b0 = *(const float4*)(brow);
            float4 b1 = *(const float4*)(brow + 4);
            float4 b2 = *(const float4*)(brow + 8);
            float4 b3 = *(const float4*)(brow + 12);
            float av[WL]  = {a0.x,a0.y,a0.z,a0.w, a1.x,a1.y,a1.z,a1.w};
            float bv[16]  = {b0.x,b0.y,b0.z,b0.w, b1.x,b1.y,b1.z,b1.w,
                             b2.x,b2.y,b2.z,b2.w, b3.x,b3.y,b3.z,b3.w};
            #pragma unroll
            for (int pw = 0; pw < PWD; ++pw)
                #pragma unroll
                for (int r = 0; r < WL; ++r)
                    acc[pw][r] += av[r] * bv[pw + r];
        }
    }

    // ---- store: ph fixed per wave; 9 pw x 2 float4 per lane
    const int ph = dhg * DPG + wv;
    float* po = out + (size_t)((b * PHD + ph) * PWD) * HW + (h0 + ly) * WW + w0 + lx * WL;
    #pragma unroll
    for (int pw = 0; pw < PWD; ++pw) {
        *(float4*)(po + (size_t)pw * HW) =
            make_float4(acc[pw][0], acc[pw][1], acc[pw][2], acc[pw][3]);
        *(float4*)(po + (size_t)pw * HW + 4) =
            make_float4(acc[pw][4], acc[pw][5], acc[pw][6], acc[pw][7]);
    }
}

extern "C" void kernel_launch(void* const* d_in, const int* in_sizes, int n_in,
                              void* d_out, int out_size, void* d_ws, size_t ws_size,
                              hipStream_t stream) {
    const float* in1 = (const float*)d_in[0];
    const float* in2 = (const float*)d_in[1];
    float* out = (float*)d_out;
    dim3 grid(9, HH / TH, BB);   // (3 wtiles x 3 dh-groups) x 6 htiles x 16 batch = 864 blocks
    corr_kernel<<<grid, NTHREADS, 0, stream>>>(in1, in2, out);
}